// Round 4
// baseline (189.253 us; speedup 1.0000x reference)
//
#include <hip/hip_runtime.h>
#include <hip/hip_bf16.h>

typedef short short8 __attribute__((ext_vector_type(8)));
typedef float floatx4 __attribute__((ext_vector_type(4)));
typedef unsigned uintx4 __attribute__((ext_vector_type(4)));

#define HWSZ 16384   // 128*128
#define WD 128
#define CD 64
#define OD 64
#define XSTR 72      // bf16 LDS row stride (144B = 9 granules)
#define OSTR 136     // fp32 epilogue stride (<=2-way banks on write/read)
#define L2E2 2.8853900817779268f   // 2*log2(e)

__device__ __forceinline__ short f2bf(float f) {
    unsigned u = __builtin_bit_cast(unsigned, f);
    u += 0x7FFFu + ((u >> 16) & 1u);     // RNE
    return (short)(u >> 16);
}

__device__ __forceinline__ unsigned pack2bf(float a, float b) {
    __hip_bfloat162 h = __float22bfloat162_rn(float2{a, b});
    unsigned u;
    __builtin_memcpy(&u, &h, 4);
    return u;
}

__device__ __forceinline__ float bf2f(short s) {
    return __builtin_bit_cast(float, ((unsigned)(unsigned short)s) << 16);
}

// one-time repack: wgt[o][c][k] fp32 -> wp[k][o][c] bf16, PRE-DOUBLED (folds the
// 2 of 1+tanh = 2*sigmoid(2s) into w; exact in bf16). Coalesced writes.
__global__ void prepack_w(const float* __restrict__ wgt, unsigned short* __restrict__ wp) {
    int idx = blockIdx.x * 256 + threadIdx.x;     // 9*64*64 = 36864
    if (idx < 9 * 64 * 64) {
        int k = idx >> 12, o = (idx >> 6) & 63, c = idx & 63;
        wp[idx] = (unsigned short)f2bf(2.0f * wgt[o * 576 + c * 9 + k]);
    }
}

// issue 32 coalesced scalar loads for one x row (or zero-fill), packed to bf16x2
__device__ __forceinline__ void load_row(const float* __restrict__ xg, bool zero,
                                         int tid, uintx4 pv[4]) {
    if (!zero) {
        #pragma unroll
        for (int it = 0; it < 4; ++it) {
            int p = it * 32 + (tid & 31);
            #pragma unroll
            for (int cc = 0; cc < 4; ++cc) {
                float a  = xg[(size_t)(2 * cc) * HWSZ + p];
                float b2 = xg[(size_t)(2 * cc + 1) * HWSZ + p];
                pv[it][cc] = pack2bf(a, b2);
            }
        }
    } else {
        #pragma unroll
        for (int it = 0; it < 4; ++it) pv[it] = (uintx4){0u, 0u, 0u, 0u};
    }
}

// write one packed row into an LDS x-buffer (slot = w+1; b128, <=2-way banks)
__device__ __forceinline__ void store_row(short* __restrict__ xbuf,
                                          const uintx4 pv[4], int tid) {
    const int g = tid >> 5;
    #pragma unroll
    for (int it = 0; it < 4; ++it) {
        int p = it * 32 + (tid & 31);
        *(uintx4*)&xbuf[(p + 1) * XSTR + g * 8] = pv[it];
    }
}

__global__ __launch_bounds__(256, 3)
void paka_kernel(const float* __restrict__ x, const float* __restrict__ gc,
                 const float* __restrict__ gs, const float* __restrict__ wgt,
                 const unsigned short* __restrict__ wp, float* __restrict__ out)
{
    __shared__ union {
        short xb2[2][130 * XSTR];   // double-buffered x rows (37.4 KB)
        float o[64 * OSTR];         // epilogue transpose buffer (34.8 KB)
    } lds;

    const int tid  = threadIdx.x;
    const int wave = tid >> 6;
    const int lane = tid & 63;

    // XCD swizzle: id%8 -> XCD (round-robin dispatch); give each XCD one batch
    // so x rows (4 MB/batch = one L2) are re-read from the local L2.
    const int id  = blockIdx.x;
    const int swz = (id & 7) * 128 + (id >> 3);
    const int b = swz >> 7;             // 8 batches
    const int h = swz & 127;            // 128 rows

    const float* xb  = x  + (size_t)b * CD * HWSZ;
    const float* gcb = gc + (size_t)b * CD * HWSZ;
    const float* gsb = gs + (size_t)b * 9 * HWSZ;

    const int row = lane & 15;
    const int q   = lane >> 4;
    const int mt0 = wave * 2;
    const int g   = tid >> 5;           // channel-group for staging

    // ---- prefetch eg = exp2(2log2e * gc[c][h][p]) for this lane's MFMA elements
    float eg[2][2][8];
    #pragma unroll
    for (int mt = 0; mt < 2; ++mt) {
        int p = (mt0 + mt) * 16 + row;
        #pragma unroll
        for (int ks = 0; ks < 2; ++ks)
            #pragma unroll
            for (int j = 0; j < 8; ++j) {
                int c = ks * 32 + q * 8 + j;
                eg[mt][ks][j] = __builtin_amdgcn_exp2f(gcb[(size_t)c * HWSZ + h * WD + p] * L2E2);
            }
    }
    // ---- prefetch esv = exp2(2log2e * gs[k][h][p]) for all 9 taps
    float esv[9][2];
    #pragma unroll
    for (int k = 0; k < 9; ++k)
        #pragma unroll
        for (int mt = 0; mt < 2; ++mt) {
            int p = (mt0 + mt) * 16 + row;
            esv[k][mt] = __builtin_amdgcn_exp2f(gsb[k * HWSZ + h * WD + p] * L2E2);
        }

    // zero the pad rows (w=-1 and w=128) of both buffers once
    if (tid < 32) {
        *(unsigned*)&lds.xb2[0][0 * XSTR + tid * 2] = 0u;
        *(unsigned*)&lds.xb2[1][0 * XSTR + tid * 2] = 0u;
    } else if (tid < 64) {
        int t = tid - 32;
        *(unsigned*)&lds.xb2[0][129 * XSTR + t * 2] = 0u;
        *(unsigned*)&lds.xb2[1][129 * XSTR + t * 2] = 0u;
    }

    floatx4 acc[2][4];
    #pragma unroll
    for (int i = 0; i < 2; ++i)
        #pragma unroll
        for (int n = 0; n < 4; ++n)
            acc[i][n] = (floatx4){0.f, 0.f, 0.f, 0.f};

    // ---- software pipeline: buf[dh&1] holds row h-1+dh
    const float* xg0 = xb + (size_t)(8 * g) * HWSZ;   // + hh*WD per row
    uintx4 pv[4];

    load_row(xg0 + (size_t)(h - 1) * WD, h == 0, tid, pv);   // row h-1
    store_row(lds.xb2[0], pv, tid);
    load_row(xg0 + (size_t)h * WD, false, tid, pv);          // issue row h
    __syncthreads();                                          // buf0 ready

    #pragma unroll
    for (int dh = 0; dh < 3; ++dh) {
        // stage next row into the other buffer (loads already in flight)
        if (dh < 2)
            store_row(lds.xb2[(dh + 1) & 1], pv, tid);
        if (dh == 0)
            load_row(xg0 + (size_t)(h + 1) * WD, h == 127, tid, pv);  // issue row h+1

        const short* rbuf = lds.xb2[dh & 1];

        #pragma unroll
        for (int dw = 0; dw < 3; ++dw) {
            const int k = dh * 3 + dw;
            #pragma unroll
            for (int ks = 0; ks < 2; ++ks) {
                // W fragments straight from global (L1/L2-hot 73.7 KB table)
                short8 bv[4];
                if (wp) {
                    const unsigned short* wk = wp + k * 4096 + ks * 32 + q * 8;
                    #pragma unroll
                    for (int nt = 0; nt < 4; ++nt)
                        bv[nt] = *(const short8*)&wk[(nt * 16 + row) * 64];
                } else {
                    #pragma unroll
                    for (int nt = 0; nt < 4; ++nt)
                        #pragma unroll
                        for (int j = 0; j < 8; ++j) {
                            int o = nt * 16 + row, c = ks * 32 + q * 8 + j;
                            bv[nt][j] = f2bf(2.0f * wgt[o * 576 + c * 9 + k]);
                        }
                }

                short8 af[2];
                #pragma unroll
                for (int mt = 0; mt < 2; ++mt) {
                    int wslot = (mt0 + mt) * 16 + row + dw;   // xl slot of w = p+dw-1
                    short8 raw = *(const short8*)&rbuf[wslot * XSTR + ks * 32 + q * 8];
                    float es = esv[k][mt];
                    #pragma unroll
                    for (int jj = 0; jj < 4; ++jj) {
                        float d0 = fmaf(eg[mt][ks][2 * jj],     es, 1.0f);
                        float d1 = fmaf(eg[mt][ks][2 * jj + 1], es, 1.0f);
                        float r0 = __builtin_amdgcn_rcpf(d0);
                        float r1 = __builtin_amdgcn_rcpf(d1);
                        float x0 = bf2f(raw[2 * jj]);
                        float x1 = bf2f(raw[2 * jj + 1]);
                        float t0 = fmaf(-x0, r0, x0);   // x * u/(1+u); the 2 lives in w
                        float t1 = fmaf(-x1, r1, x1);
                        ((unsigned*)&af[mt])[jj] = pack2bf(t0, t1);
                    }
                }
                #pragma unroll
                for (int nt = 0; nt < 4; ++nt) {
                    acc[0][nt] = __builtin_amdgcn_mfma_f32_16x16x32_bf16(af[0], bv[nt], acc[0][nt], 0, 0, 0);
                    acc[1][nt] = __builtin_amdgcn_mfma_f32_16x16x32_bf16(af[1], bv[nt], acc[1][nt], 0, 0, 0);
                }
            }
        }
        __syncthreads();   // next phase's buffer fully staged; this buffer free
    }

    // D layout: col(=o) = lane&15, rowD(=p) = (lane>>4)*4 + reg. Transpose via LDS.
    #pragma unroll
    for (int i = 0; i < 2; ++i) {
        int prow = (mt0 + i) * 16 + q * 4;
        #pragma unroll
        for (int nt = 0; nt < 4; ++nt) {
            int o = nt * 16 + row;
            *(floatx4*)&lds.o[o * OSTR + prow] = acc[i][nt];
        }
    }

    __syncthreads();

    // coalesced float4 stores: out[b][o][h][0..127]
    float* outb = out + ((size_t)b * OD) * HWSZ + h * WD;
    #pragma unroll
    for (int it = 0; it < 8; ++it) {
        int idx = it * 256 + tid;              // 2048 float4s
        int o = idx >> 5, p4 = (idx & 31) * 4;
        *(floatx4*)&outb[(size_t)o * HWSZ + p4] = *(const floatx4*)&lds.o[o * OSTR + p4];
    }
}

extern "C" void kernel_launch(void* const* d_in, const int* in_sizes, int n_in,
                              void* d_out, int out_size, void* d_ws, size_t ws_size,
                              hipStream_t stream) {
    const float* x   = (const float*)d_in[0];
    const float* gcp = (const float*)d_in[1];
    const float* gsp = (const float*)d_in[2];
    const float* wgt = (const float*)d_in[3];
    float* out = (float*)d_out;

    const bool use_wp = ws_size >= (size_t)(9 * 64 * 64 * sizeof(unsigned short));
    unsigned short* wp = use_wp ? (unsigned short*)d_ws : nullptr;
    if (use_wp)
        prepack_w<<<dim3(144), dim3(256), 0, stream>>>(wgt, wp);
    paka_kernel<<<dim3(1024), dim3(256), 0, stream>>>(x, gcp, gsp, wgt, wp, out);
}